// Round 2
// baseline (2540.638 us; speedup 1.0000x reference)
//
#include <hip/hip_runtime.h>
#include <hip/hip_bf16.h>
#include <stdint.h>

typedef unsigned short u16;
typedef unsigned int   u32;

#define B_   16
#define H_   112
#define W_   112
#define C_   128
#define SH_  3
#define NTOK 49
#define SCALE 0.17677669529663687f   // 1/sqrt(32)

__device__ __forceinline__ float bflo(u32 u) {
    u32 i = u << 16; float f; __builtin_memcpy(&f, &i, 4); return f;
}
__device__ __forceinline__ float bfhi(u32 u) {
    u32 i = u & 0xffff0000u; float f; __builtin_memcpy(&f, &i, 4); return f;
}
__device__ __forceinline__ u16 f2bf(float f) {
    u32 i; __builtin_memcpy(&i, &f, 4);
    u32 lsb = (i >> 16) & 1u;
    i += 0x7fffu + lsb;
    return (u16)(i >> 16);
}

// ---------------------------------------------------------------------------
// Kernel A: one block per 7x7 window (4096 blocks). f32 I/O, bf16 LDS tiles.
// LN1 + cyclic shift -> LDS; qkv (column-accumulator); 4-head attention
// (wave == head, lane == query row); proj; writes x1 = x + attn to d_out.
// LDS ~58 KB -> 2 blocks/CU.
// ---------------------------------------------------------------------------
__global__ __launch_bounds__(256, 2) void swin_attn_k(
    const float* __restrict__ x,   const float* __restrict__ n1g, const float* __restrict__ n1b,
    const float* __restrict__ qkvw,const float* __restrict__ qkvb,const float* __restrict__ rel,
    const float* __restrict__ projw,const float* __restrict__ projb, float* __restrict__ out)
{
    __shared__ u16  sxn[50 * 132];              // xn tokens (bf16); later reused as attn-out
    __shared__ u16  sq[4 * 49 * 36];            // q (pre-scaled), pad 36 for alignment
    __shared__ u16  sk[4 * 49 * 36];
    __shared__ u16  sv[4 * 49 * 36];
    __shared__ float srel[676];                 // rel_table [169][4] f32

    const int tid  = threadIdx.x;
    const int wave = tid >> 6, lane = tid & 63;
    const int m  = blockIdx.x;
    const int b  = m >> 8;
    const int hb = (m >> 4) & 15;
    const int wb = m & 15;

    for (int i = tid; i < 676; i += 256) srel[i] = rel[i];

    // ---- LN1 over shifted source tokens -> sxn (bf16) ----
    for (int t = wave; t < NTOK; t += 4) {
        int hs = hb * 7 + t / 7 + SH_; if (hs >= H_) hs -= H_;
        int ws = wb * 7 + t % 7 + SH_; if (ws >= W_) ws -= W_;
        const float* px = x + (((size_t)b * H_ + hs) * W_ + ws) * C_;
        const int c0 = lane * 2;
        float2 pv = *(const float2*)(px + c0);
        float v0 = pv.x, v1 = pv.y;
        float s = v0 + v1, sq2 = v0 * v0 + v1 * v1;
        #pragma unroll
        for (int o = 1; o < 64; o <<= 1) { s += __shfl_xor(s, o); sq2 += __shfl_xor(sq2, o); }
        float mean = s * (1.0f / 128.0f);
        float var  = sq2 * (1.0f / 128.0f) - mean * mean;
        float rstd = rsqrtf(var + 1e-5f);
        float2 gv = *(const float2*)(n1g + c0);
        float2 bv = *(const float2*)(n1b + c0);
        float o0 = (v0 - mean) * rstd * gv.x + bv.x;
        float o1 = (v1 - mean) * rstd * gv.y + bv.y;
        *(u32*)&sxn[t * 132 + c0] = ((u32)f2bf(o0)) | (((u32)f2bf(o1)) << 16);
    }
    __syncthreads();

    // ---- qkv: thread owns output column j, accumulates over all 49 tokens ----
    for (int j = tid; j < 384; j += 256) {
        float acc[49];
        #pragma unroll
        for (int t = 0; t < 49; ++t) acc[t] = 0.0f;
        for (int c0 = 0; c0 < 128; c0 += 4) {
            float w0 = qkvw[(c0 + 0) * 384 + j];
            float w1 = qkvw[(c0 + 1) * 384 + j];
            float w2 = qkvw[(c0 + 2) * 384 + j];
            float w3 = qkvw[(c0 + 3) * 384 + j];
            #pragma unroll
            for (int t = 0; t < 49; ++t) {
                uint2 xv = *(const uint2*)&sxn[t * 132 + c0];
                acc[t] += bflo(xv.x) * w0 + bfhi(xv.x) * w1 + bflo(xv.y) * w2 + bfhi(xv.y) * w3;
            }
        }
        float bias = qkvb[j];
        u16* dst = (j < 128) ? sq : (j < 256 ? sk : sv);
        const int jj = j & 127;
        const int h = jj >> 5, d = jj & 31;
        const float sc = (j < 128) ? SCALE : 1.0f;   // fold softmax scale into q
        #pragma unroll
        for (int t = 0; t < 49; ++t) dst[(h * 49 + t) * 36 + d] = f2bf((acc[t] + bias) * sc);
    }
    __syncthreads();

    // ---- attention: wave = head, lane = query row ----
    {
        const int h = wave;
        const int r = lane;
        if (r < 49) {
            const int ri = r / 7, rc = r % 7;
            float qr[32];
            #pragma unroll
            for (int d0 = 0; d0 < 32; d0 += 4) {
                uint2 qv = *(const uint2*)&sq[(h * 49 + r) * 36 + d0];
                qr[d0] = bflo(qv.x); qr[d0 + 1] = bfhi(qv.x);
                qr[d0 + 2] = bflo(qv.y); qr[d0 + 3] = bfhi(qv.y);
            }
            const bool masked = (hb == 15) || (wb == 15);
            int regr = 0;
            if (masked) {
                int hs = hb * 7 + ri, ws = wb * 7 + rc;
                regr = (hs < 105 ? 0 : (hs < 109 ? 1 : 2)) * 3 + (ws < 105 ? 0 : (ws < 109 ? 1 : 2));
            }
            float s[49];
            #pragma unroll
            for (int j = 0; j < 49; ++j) {
                float a = 0.0f;
                #pragma unroll
                for (int d0 = 0; d0 < 32; d0 += 4) {
                    uint2 kv = *(const uint2*)&sk[(h * 49 + j) * 36 + d0];
                    a += qr[d0] * bflo(kv.x) + qr[d0 + 1] * bfhi(kv.x)
                       + qr[d0 + 2] * bflo(kv.y) + qr[d0 + 3] * bfhi(kv.y);
                }
                const int ji = j / 7, jc = j % 7;
                a += srel[((ri - ji + 6) * 13 + (rc - jc + 6)) * 4 + h];
                if (masked) {
                    int hs = hb * 7 + ji, ws = wb * 7 + jc;
                    int regj = (hs < 105 ? 0 : (hs < 109 ? 1 : 2)) * 3 + (ws < 105 ? 0 : (ws < 109 ? 1 : 2));
                    if (regj != regr) a -= 100.0f;
                }
                s[j] = a;
            }
            float mx = s[0];
            #pragma unroll
            for (int j = 1; j < 49; ++j) mx = fmaxf(mx, s[j]);
            float sum = 0.0f;
            #pragma unroll
            for (int j = 0; j < 49; ++j) { float p = __expf(s[j] - mx); sum += p; s[j] = p; }
            const float inv = 1.0f / sum;
            float o[32];
            #pragma unroll
            for (int d = 0; d < 32; ++d) o[d] = 0.0f;
            #pragma unroll
            for (int j = 0; j < 49; ++j) {
                const float p = s[j];
                #pragma unroll
                for (int d0 = 0; d0 < 32; d0 += 4) {
                    uint2 vv = *(const uint2*)&sv[(h * 49 + j) * 36 + d0];
                    o[d0]     += p * bflo(vv.x); o[d0 + 1] += p * bfhi(vv.x);
                    o[d0 + 2] += p * bflo(vv.y); o[d0 + 3] += p * bfhi(vv.y);
                }
            }
            // write head slice into attn-out (aliases sxn; qkv readers barriered above)
            #pragma unroll
            for (int d0 = 0; d0 < 32; d0 += 2) {
                u32 pk = ((u32)f2bf(o[d0] * inv)) | (((u32)f2bf(o[d0 + 1] * inv)) << 16);
                *(u32*)&sxn[r * 132 + h * 32 + d0] = pk;
            }
        }
    }
    __syncthreads();

    // ---- proj + residual + unshift scatter (writes x1 to d_out, f32) ----
    {
        const int c = tid & 127, th = tid >> 7;
        const int t0 = th * 25;                 // th==1 covers tokens 25..48 (+1 dummy row 49)
        float acc[25];
        #pragma unroll
        for (int t = 0; t < 25; ++t) acc[t] = 0.0f;
        for (int k0 = 0; k0 < 128; k0 += 4) {
            float w0 = projw[(k0 + 0) * 128 + c];
            float w1 = projw[(k0 + 1) * 128 + c];
            float w2 = projw[(k0 + 2) * 128 + c];
            float w3 = projw[(k0 + 3) * 128 + c];
            #pragma unroll
            for (int t = 0; t < 25; ++t) {
                uint2 av = *(const uint2*)&sxn[(t0 + t) * 132 + k0];
                acc[t] += bflo(av.x) * w0 + bfhi(av.x) * w1 + bflo(av.y) * w2 + bfhi(av.y) * w3;
            }
        }
        const float pb = projb[c];
        for (int t = 0; t < 25; ++t) {
            const int tok = t0 + t;
            if (tok >= 49) break;               // uniform across the wave
            int hs = hb * 7 + tok / 7 + SH_; if (hs >= H_) hs -= H_;
            int ws = wb * 7 + tok % 7 + SH_; if (ws >= W_) ws -= W_;
            const size_t oi = (((size_t)b * H_ + hs) * W_ + ws) * C_ + c;
            out[oi] = acc[t] + pb + x[oi];
        }
    }
}

// ---------------------------------------------------------------------------
// Kernel B: MLP. 32 tokens per block (6272 blocks), in-place on d_out (f32):
// out = x1 + fc2(gelu(fc1(LN2(x1)))).  LDS ~49 KB -> 3 blocks/CU.
// ---------------------------------------------------------------------------
__global__ __launch_bounds__(256, 3) void swin_mlp_k(
    float* __restrict__ xio, const float* __restrict__ n2g, const float* __restrict__ n2b,
    const float* __restrict__ f1w, const float* __restrict__ f1b,
    const float* __restrict__ f2w, const float* __restrict__ f2b)
{
    __shared__ float sxn[32 * 132];
    __shared__ u16   sh[32 * 512];
    const int tid = threadIdx.x, wave = tid >> 6, lane = tid & 63;
    const size_t tok0 = (size_t)blockIdx.x * 32;

    // ---- LN2 ----
    for (int t = wave; t < 32; t += 4) {
        const float* px = xio + (tok0 + t) * C_;
        const int c0 = lane * 2;
        float2 pv = *(const float2*)(px + c0);
        float v0 = pv.x, v1 = pv.y;
        float s = v0 + v1, q = v0 * v0 + v1 * v1;
        #pragma unroll
        for (int o = 1; o < 64; o <<= 1) { s += __shfl_xor(s, o); q += __shfl_xor(q, o); }
        float mean = s * (1.0f / 128.0f), var = q * (1.0f / 128.0f) - mean * mean;
        float rstd = rsqrtf(var + 1e-5f);
        float2 gv = *(const float2*)(n2g + c0);
        float2 bv = *(const float2*)(n2b + c0);
        sxn[t * 132 + c0]     = (v0 - mean) * rstd * gv.x + bv.x;
        sxn[t * 132 + c0 + 1] = (v1 - mean) * rstd * gv.y + bv.y;
    }
    __syncthreads();

    // ---- fc1 + exact GELU -> sh (bf16) ----
    {
        const int j = tid;
        float a0[32], a1[32];
        #pragma unroll
        for (int t = 0; t < 32; ++t) { a0[t] = 0.0f; a1[t] = 0.0f; }
        for (int c0 = 0; c0 < 128; c0 += 2) {
            float w00 = f1w[(c0 + 0) * 512 + j];
            float w01 = f1w[(c0 + 1) * 512 + j];
            float w10 = f1w[(c0 + 0) * 512 + j + 256];
            float w11 = f1w[(c0 + 1) * 512 + j + 256];
            #pragma unroll
            for (int t = 0; t < 32; ++t) {
                float2 xv = *(const float2*)&sxn[t * 132 + c0];
                a0[t] += xv.x * w00 + xv.y * w01;
                a1[t] += xv.x * w10 + xv.y * w11;
            }
        }
        const float bb0 = f1b[j], bb1 = f1b[j + 256];
        #pragma unroll
        for (int t = 0; t < 32; ++t) {
            float h0 = a0[t] + bb0, h1 = a1[t] + bb1;
            h0 = 0.5f * h0 * (1.0f + erff(h0 * 0.70710678118654752f));
            h1 = 0.5f * h1 * (1.0f + erff(h1 * 0.70710678118654752f));
            sh[t * 512 + j]       = f2bf(h0);
            sh[t * 512 + j + 256] = f2bf(h1);
        }
    }
    __syncthreads();

    // ---- fc2 + residual (in place, f32) ----
    {
        const int c = tid & 127, th = tid >> 7;
        const int t0 = th * 16;
        float acc[16];
        #pragma unroll
        for (int t = 0; t < 16; ++t) acc[t] = 0.0f;
        for (int k0 = 0; k0 < 512; k0 += 4) {
            float w0 = f2w[(k0 + 0) * 128 + c];
            float w1 = f2w[(k0 + 1) * 128 + c];
            float w2 = f2w[(k0 + 2) * 128 + c];
            float w3 = f2w[(k0 + 3) * 128 + c];
            #pragma unroll
            for (int t = 0; t < 16; ++t) {
                uint2 hv = *(const uint2*)&sh[(t0 + t) * 512 + k0];
                acc[t] += bflo(hv.x) * w0 + bfhi(hv.x) * w1 + bflo(hv.y) * w2 + bfhi(hv.y) * w3;
            }
        }
        const float cb = f2b[c];
        #pragma unroll
        for (int t = 0; t < 16; ++t) {
            const size_t oi = (tok0 + t0 + t) * C_ + c;
            xio[oi] = acc[t] + cb + xio[oi];
        }
    }
}

extern "C" void kernel_launch(void* const* d_in, const int* in_sizes, int n_in,
                              void* d_out, int out_size, void* d_ws, size_t ws_size,
                              hipStream_t stream)
{
    const float* x    = (const float*)d_in[0];
    const float* n1g  = (const float*)d_in[1];
    const float* n1b  = (const float*)d_in[2];
    const float* qkvw = (const float*)d_in[3];
    const float* qkvb = (const float*)d_in[4];
    const float* rel  = (const float*)d_in[5];
    const float* pw   = (const float*)d_in[6];
    const float* pb   = (const float*)d_in[7];
    const float* n2g  = (const float*)d_in[8];
    const float* n2b  = (const float*)d_in[9];
    const float* f1w  = (const float*)d_in[10];
    const float* f1b  = (const float*)d_in[11];
    const float* f2w  = (const float*)d_in[12];
    const float* f2b  = (const float*)d_in[13];
    float* out = (float*)d_out;

    swin_attn_k<<<4096, 256, 0, stream>>>(x, n1g, n1b, qkvw, qkvb, rel, pw, pb, out);
    swin_mlp_k<<<6272, 256, 0, stream>>>(out, n2g, n2b, f1w, f1b, f2w, f2b);
}

// Round 3
// 469.200 us; speedup vs baseline: 5.4148x; 5.4148x over previous
//
#include <hip/hip_runtime.h>
#include <hip/hip_bf16.h>
#include <stdint.h>

typedef unsigned short u16;
typedef unsigned int   u32;
typedef __attribute__((ext_vector_type(8))) short bh8;   // 8 bf16 (4 VGPRs)
typedef __attribute__((ext_vector_type(4))) float f32x4; // MFMA C/D

#define B_   16
#define H_   112
#define W_   112
#define C_   128
#define SH_  3
#define SCALE 0.17677669529663687f   // 1/sqrt(32)

// d_ws layout (u16 units)
#define WS_QKV  0        // qkvwT [384][128]
#define WS_PROJ 49152    // projwT [128][128]
#define WS_F1   65536    // f1wT  [512][128]
#define WS_F2   131072   // f2wT  [128][512]

// attn smem layout (u16 units)
#define XNP   136        // xn row pitch
#define SQK0  8704       // per head: q[64][40] @ +0, k[64][40] @ +2560 ; P[64][72] aliases
#define SVT0  29184      // per head: vt[32][72]
#define SREL0 38400      // f32[676]
#define SM_TOT 39752

__device__ __forceinline__ u16 f2bf(float f) {
    u32 i; __builtin_memcpy(&i, &f, 4);
    u32 lsb = (i >> 16) & 1u;
    i += 0x7fffu + lsb;
    return (u16)(i >> 16);
}
__device__ __forceinline__ float bf2f(u16 u) {
    u32 i = ((u32)u) << 16; float f; __builtin_memcpy(&f, &i, 4); return f;
}

// ---------------------------------------------------------------------------
// Prep: transpose+convert weights f32 -> bf16 into ws.
// ---------------------------------------------------------------------------
__global__ void prep_w_k(const float* __restrict__ qkvw, const float* __restrict__ projw,
                         const float* __restrict__ f1w,  const float* __restrict__ f2w,
                         u16* __restrict__ ws)
{
    int idx = blockIdx.x * 256 + threadIdx.x;
    if (idx < 49152) {                       // qkvw [128][384] -> [384][128]
        int r = idx / 384, c = idx % 384;
        ws[WS_QKV + c * 128 + r] = f2bf(qkvw[idx]);
    } else if (idx < 65536) {                // projw [128][128] -> T
        int i = idx - 49152; int r = i >> 7, c = i & 127;
        ws[WS_PROJ + c * 128 + r] = f2bf(projw[i]);
    } else if (idx < 131072) {               // f1w [128][512] -> [512][128]
        int i = idx - 65536; int r = i >> 9, c = i & 511;
        ws[WS_F1 + c * 128 + r] = f2bf(f1w[i]);
    } else if (idx < 196608) {               // f2w [512][128] -> [128][512]
        int i = idx - 131072; int r = i >> 7, c = i & 127;
        ws[WS_F2 + c * 512 + r] = f2bf(f2w[i]);
    }
}

// ---------------------------------------------------------------------------
// Attention block kernel: 1 block = one 7x7 window, 4 waves, MFMA everywhere.
// ---------------------------------------------------------------------------
__global__ __launch_bounds__(256, 2) void swin_attn_k(
    const float* __restrict__ x,   const float* __restrict__ n1g, const float* __restrict__ n1b,
    const float* __restrict__ qkvb,const float* __restrict__ rel,
    const float* __restrict__ projb, const u16* __restrict__ ws, float* __restrict__ out)
{
    __shared__ u16 sm[SM_TOT];
    float* srel = (float*)&sm[SREL0];

    const int tid  = threadIdx.x;
    const int wave = tid >> 6, lane = tid & 63;
    const int c15 = lane & 15, g = lane >> 4;
    const int m  = blockIdx.x;
    const int b  = m >> 8;
    const int hb = (m >> 4) & 15;
    const int wb = m & 15;

    for (int i = tid; i < 676; i += 256) srel[i] = rel[i];

    // ---- LN1 + cyclic shift -> xn bf16 [64][136]; rows 49..63 zero ----
    for (int t = wave; t < 64; t += 4) {
        const int c0 = lane * 2;
        if (t < 49) {
            int hs = hb * 7 + t / 7 + SH_; if (hs >= H_) hs -= H_;
            int wss = wb * 7 + t % 7 + SH_; if (wss >= W_) wss -= W_;
            const float* px = x + (((size_t)b * H_ + hs) * W_ + wss) * C_;
            float2 pv = *(const float2*)(px + c0);
            float v0 = pv.x, v1 = pv.y;
            float s = v0 + v1, sq2 = v0 * v0 + v1 * v1;
            #pragma unroll
            for (int o = 1; o < 64; o <<= 1) { s += __shfl_xor(s, o); sq2 += __shfl_xor(sq2, o); }
            float mean = s * (1.0f / 128.0f);
            float var  = sq2 * (1.0f / 128.0f) - mean * mean;
            float rstd = rsqrtf(var + 1e-5f);
            float2 gv = *(const float2*)(n1g + c0);
            float2 bv = *(const float2*)(n1b + c0);
            float o0 = (v0 - mean) * rstd * gv.x + bv.x;
            float o1 = (v1 - mean) * rstd * gv.y + bv.y;
            *(u32*)&sm[t * XNP + c0] = ((u32)f2bf(o0)) | (((u32)f2bf(o1)) << 16);
        } else {
            *(u32*)&sm[t * XNP + c0] = 0u;
        }
    }
    __syncthreads();

    // ---- qkv GEMM [64x128]@[128x384]; wave takes coltiles {w, w+4, ...} ----
    {
        bh8 af[4][4];
        #pragma unroll
        for (int rt = 0; rt < 4; ++rt)
            #pragma unroll
            for (int kc = 0; kc < 4; ++kc)
                af[rt][kc] = *(const bh8*)&sm[(rt * 16 + c15) * XNP + kc * 32 + g * 8];

        for (int c = wave; c < 24; c += 4) {
            const int j = c * 16 + c15;
            bh8 bf_[4];
            #pragma unroll
            for (int kc = 0; kc < 4; ++kc)
                bf_[kc] = *(const bh8*)&ws[WS_QKV + j * 128 + kc * 32 + g * 8];
            f32x4 acc[4];
            #pragma unroll
            for (int rt = 0; rt < 4; ++rt) {
                acc[rt] = (f32x4){0.f, 0.f, 0.f, 0.f};
                #pragma unroll
                for (int kc = 0; kc < 4; ++kc)
                    acc[rt] = __builtin_amdgcn_mfma_f32_16x16x32_bf16(af[rt][kc], bf_[kc], acc[rt], 0, 0, 0);
            }
            const float bias = qkvb[j];
            int base; float sc = 1.0f; bool isv = false;
            if (c < 8)       { base = SQK0 + (c >> 1) * 5120;               sc = SCALE; }
            else if (c < 16) { base = SQK0 + ((c - 8) >> 1) * 5120 + 2560; }
            else             { base = SVT0 + ((c - 16) >> 1) * 2304;        isv = true; }
            const int d = (c & 1) * 16 + c15;
            #pragma unroll
            for (int rt = 0; rt < 4; ++rt)
                #pragma unroll
                for (int jr = 0; jr < 4; ++jr) {
                    const int row = rt * 16 + g * 4 + jr;
                    const u16 v = f2bf((acc[rt][jr] + bias) * sc);
                    sm[isv ? (base + d * 72 + row) : (base + row * 40 + d)] = v;
                }
        }
    }
    __syncthreads();

    // ---- per-wave attention core: head h = wave ----
    {
        const int h = wave;
        const int qb = SQK0 + h * 5120;
        const int kb = qb + 2560;
        const int vb = SVT0 + h * 2304;

        bh8 qa[4];
        #pragma unroll
        for (int rt = 0; rt < 4; ++rt)
            qa[rt] = *(const bh8*)&sm[qb + (rt * 16 + c15) * 40 + g * 8];

        f32x4 s[4][4];
        #pragma unroll
        for (int ct = 0; ct < 4; ++ct) {
            bh8 kf = *(const bh8*)&sm[kb + (ct * 16 + c15) * 40 + g * 8];
            #pragma unroll
            for (int rt = 0; rt < 4; ++rt)
                s[rt][ct] = __builtin_amdgcn_mfma_f32_16x16x32_bf16(qa[rt], kf, (f32x4){0.f,0.f,0.f,0.f}, 0, 0, 0);
        }

        // bias + mask
        const bool mblk = (hb == 15) || (wb == 15);
        int kiv[4], kcv[4], regk[4]; bool kok[4];
        #pragma unroll
        for (int ct = 0; ct < 4; ++ct) {
            const int key = ct * 16 + c15;
            kok[ct] = key < 49;
            const int kk = kok[ct] ? key : 0;
            kiv[ct] = kk / 7; kcv[ct] = kk % 7;
            if (mblk) {
                int hs = hb * 7 + kiv[ct], wss = wb * 7 + kcv[ct];
                regk[ct] = (hs < 105 ? 0 : (hs < 109 ? 1 : 2)) * 3 + (wss < 105 ? 0 : (wss < 109 ? 1 : 2));
            } else regk[ct] = 0;
        }
        #pragma unroll
        for (int rt = 0; rt < 4; ++rt)
            #pragma unroll
            for (int jr = 0; jr < 4; ++jr) {
                const int q = rt * 16 + g * 4 + jr;
                const int qq = q < 49 ? q : 0;
                const int qi = qq / 7, qc = qq % 7;
                int regq = 0;
                if (mblk) {
                    int hs = hb * 7 + qi, wss = wb * 7 + qc;
                    regq = (hs < 105 ? 0 : (hs < 109 ? 1 : 2)) * 3 + (wss < 105 ? 0 : (wss < 109 ? 1 : 2));
                }
                #pragma unroll
                for (int ct = 0; ct < 4; ++ct) {
                    if (!kok[ct]) { s[rt][ct][jr] = -1e30f; continue; }
                    float a = s[rt][ct][jr];
                    a += srel[((qi - kiv[ct] + 6) * 13 + (qc - kcv[ct] + 6)) * 4 + h];
                    if (mblk && regq != regk[ct]) a -= 100.0f;
                    s[rt][ct][jr] = a;
                }
            }

        // softmax per query row: in-lane over ct + 16-lane butterfly
        #pragma unroll
        for (int rt = 0; rt < 4; ++rt)
            #pragma unroll
            for (int jr = 0; jr < 4; ++jr) {
                float mx = fmaxf(fmaxf(s[rt][0][jr], s[rt][1][jr]), fmaxf(s[rt][2][jr], s[rt][3][jr]));
                #pragma unroll
                for (int o = 1; o < 16; o <<= 1) mx = fmaxf(mx, __shfl_xor(mx, o));
                float sum = 0.f;
                #pragma unroll
                for (int ct = 0; ct < 4; ++ct) { float p = __expf(s[rt][ct][jr] - mx); s[rt][ct][jr] = p; sum += p; }
                #pragma unroll
                for (int o = 1; o < 16; o <<= 1) sum += __shfl_xor(sum, o);
                const float inv = 1.0f / sum;
                #pragma unroll
                for (int ct = 0; ct < 4; ++ct) s[rt][ct][jr] *= inv;
            }

        // P -> LDS (aliases q/k region of this head; wave-local)
        __builtin_amdgcn_s_waitcnt(0xc07f);   // lgkmcnt(0): all q/k ds_reads done
        #pragma unroll
        for (int rt = 0; rt < 4; ++rt)
            #pragma unroll
            for (int ct = 0; ct < 4; ++ct)
                #pragma unroll
                for (int jr = 0; jr < 4; ++jr)
                    sm[qb + (rt * 16 + g * 4 + jr) * 72 + ct * 16 + c15] = f2bf(s[rt][ct][jr]);

        // PV: out[64][32] = P[64][64] @ V[64][32]
        f32x4 o[4][2];
        #pragma unroll
        for (int rt = 0; rt < 4; ++rt) { o[rt][0] = (f32x4){0,0,0,0}; o[rt][1] = (f32x4){0,0,0,0}; }
        #pragma unroll
        for (int kc = 0; kc < 2; ++kc) {
            bh8 pa[4];
            #pragma unroll
            for (int rt = 0; rt < 4; ++rt)
                pa[rt] = *(const bh8*)&sm[qb + (rt * 16 + c15) * 72 + kc * 32 + g * 8];
            #pragma unroll
            for (int ct = 0; ct < 2; ++ct) {
                bh8 vf = *(const bh8*)&sm[vb + (ct * 16 + c15) * 72 + kc * 32 + g * 8];
                #pragma unroll
                for (int rt = 0; rt < 4; ++rt)
                    o[rt][ct] = __builtin_amdgcn_mfma_f32_16x16x32_bf16(pa[rt], vf, o[rt][ct], 0, 0, 0);
            }
        }
        // attn-out -> ao (reuses xn buffer), cols h*32..h*32+31
        #pragma unroll
        for (int rt = 0; rt < 4; ++rt)
            #pragma unroll
            for (int ct = 0; ct < 2; ++ct)
                #pragma unroll
                for (int jr = 0; jr < 4; ++jr)
                    sm[(rt * 16 + g * 4 + jr) * XNP + h * 32 + ct * 16 + c15] = f2bf(o[rt][ct][jr]);
    }
    __syncthreads();

    // ---- proj [64x128]@[128x128] + residual + unshift scatter ----
    {
        bh8 af[4][4];
        #pragma unroll
        for (int rt = 0; rt < 4; ++rt)
            #pragma unroll
            for (int kc = 0; kc < 4; ++kc)
                af[rt][kc] = *(const bh8*)&sm[(rt * 16 + c15) * XNP + kc * 32 + g * 8];
        f32x4 pacc[4][2];
        #pragma unroll
        for (int rt = 0; rt < 4; ++rt) { pacc[rt][0] = (f32x4){0,0,0,0}; pacc[rt][1] = (f32x4){0,0,0,0}; }
        #pragma unroll
        for (int ct2 = 0; ct2 < 2; ++ct2) {
            const int col = (wave * 2 + ct2) * 16 + c15;
            #pragma unroll
            for (int kc = 0; kc < 4; ++kc) {
                bh8 wf = *(const bh8*)&ws[WS_PROJ + col * 128 + kc * 32 + g * 8];
                #pragma unroll
                for (int rt = 0; rt < 4; ++rt)
                    pacc[rt][ct2] = __builtin_amdgcn_mfma_f32_16x16x32_bf16(af[rt][kc], wf, pacc[rt][ct2], 0, 0, 0);
            }
        }
        #pragma unroll
        for (int rt = 0; rt < 4; ++rt)
            #pragma unroll
            for (int jr = 0; jr < 4; ++jr) {
                const int t = rt * 16 + g * 4 + jr;
                if (t < 49) {
                    int hs = hb * 7 + t / 7 + SH_; if (hs >= H_) hs -= H_;
                    int wss = wb * 7 + t % 7 + SH_; if (wss >= W_) wss -= W_;
                    #pragma unroll
                    for (int ct2 = 0; ct2 < 2; ++ct2) {
                        const int col = (wave * 2 + ct2) * 16 + c15;
                        const size_t oi = (((size_t)b * H_ + hs) * W_ + wss) * C_ + col;
                        out[oi] = pacc[rt][ct2][jr] + projb[col] + x[oi];
                    }
                }
            }
    }
}

// ---------------------------------------------------------------------------
// MLP kernel: 32 tokens/block, MFMA fc1/fc2, in-place on d_out.
// ---------------------------------------------------------------------------
__global__ __launch_bounds__(256, 3) void swin_mlp_k(
    float* __restrict__ xio, const float* __restrict__ n2g, const float* __restrict__ n2b,
    const float* __restrict__ f1b, const float* __restrict__ f2b, const u16* __restrict__ ws)
{
    __shared__ u16 sm2[32 * XNP + 32 * 520];   // xn [32][136] @0 ; h [32][520] @4352
    const int tid = threadIdx.x, wave = tid >> 6, lane = tid & 63;
    const int c15 = lane & 15, g = lane >> 4;
    const size_t tok0 = (size_t)blockIdx.x * 32;

    // ---- LN2 ----
    for (int t = wave; t < 32; t += 4) {
        const float* px = xio + (tok0 + t) * C_;
        const int c0 = lane * 2;
        float2 pv = *(const float2*)(px + c0);
        float v0 = pv.x, v1 = pv.y;
        float s = v0 + v1, q = v0 * v0 + v1 * v1;
        #pragma unroll
        for (int o = 1; o < 64; o <<= 1) { s += __shfl_xor(s, o); q += __shfl_xor(q, o); }
        float mean = s * (1.0f / 128.0f), var = q * (1.0f / 128.0f) - mean * mean;
        float rstd = rsqrtf(var + 1e-5f);
        float2 gv = *(const float2*)(n2g + c0);
        float2 bv = *(const float2*)(n2b + c0);
        float o0 = (v0 - mean) * rstd * gv.x + bv.x;
        float o1 = (v1 - mean) * rstd * gv.y + bv.y;
        *(u32*)&sm2[t * XNP + c0] = ((u32)f2bf(o0)) | (((u32)f2bf(o1)) << 16);
    }
    __syncthreads();

    // ---- fc1 + exact GELU -> h bf16 ----
    {
        bh8 af[2][4];
        #pragma unroll
        for (int rt = 0; rt < 2; ++rt)
            #pragma unroll
            for (int kc = 0; kc < 4; ++kc)
                af[rt][kc] = *(const bh8*)&sm2[(rt * 16 + c15) * XNP + kc * 32 + g * 8];
        for (int ct8 = 0; ct8 < 8; ++ct8) {
            const int j = (wave * 8 + ct8) * 16 + c15;
            bh8 wf[4];
            #pragma unroll
            for (int kc = 0; kc < 4; ++kc)
                wf[kc] = *(const bh8*)&ws[WS_F1 + j * 128 + kc * 32 + g * 8];
            f32x4 acc[2];
            #pragma unroll
            for (int rt = 0; rt < 2; ++rt) {
                acc[rt] = (f32x4){0,0,0,0};
                #pragma unroll
                for (int kc = 0; kc < 4; ++kc)
                    acc[rt] = __builtin_amdgcn_mfma_f32_16x16x32_bf16(af[rt][kc], wf[kc], acc[rt], 0, 0, 0);
            }
            const float bias = f1b[j];
            #pragma unroll
            for (int rt = 0; rt < 2; ++rt)
                #pragma unroll
                for (int jr = 0; jr < 4; ++jr) {
                    float h0 = acc[rt][jr] + bias;
                    h0 = 0.5f * h0 * (1.0f + erff(h0 * 0.70710678118654752f));
                    sm2[32 * XNP + (rt * 16 + g * 4 + jr) * 520 + j] = f2bf(h0);
                }
        }
    }
    __syncthreads();

    // ---- fc2 + residual (in place) ----
    {
        f32x4 acc[2][2];
        acc[0][0] = (f32x4){0,0,0,0}; acc[0][1] = (f32x4){0,0,0,0};
        acc[1][0] = (f32x4){0,0,0,0}; acc[1][1] = (f32x4){0,0,0,0};
        #pragma unroll
        for (int kc = 0; kc < 16; ++kc) {
            bh8 a0 = *(const bh8*)&sm2[32 * XNP + (c15) * 520 + kc * 32 + g * 8];
            bh8 a1 = *(const bh8*)&sm2[32 * XNP + (16 + c15) * 520 + kc * 32 + g * 8];
            #pragma unroll
            for (int ct2 = 0; ct2 < 2; ++ct2) {
                const int col = (wave * 2 + ct2) * 16 + c15;
                bh8 wf = *(const bh8*)&ws[WS_F2 + col * 512 + kc * 32 + g * 8];
                acc[0][ct2] = __builtin_amdgcn_mfma_f32_16x16x32_bf16(a0, wf, acc[0][ct2], 0, 0, 0);
                acc[1][ct2] = __builtin_amdgcn_mfma_f32_16x16x32_bf16(a1, wf, acc[1][ct2], 0, 0, 0);
            }
        }
        #pragma unroll
        for (int rt = 0; rt < 2; ++rt)
            #pragma unroll
            for (int ct2 = 0; ct2 < 2; ++ct2) {
                const int col = (wave * 2 + ct2) * 16 + c15;
                const float cb = f2b[col];
                #pragma unroll
                for (int jr = 0; jr < 4; ++jr) {
                    const size_t oi = (tok0 + rt * 16 + g * 4 + jr) * C_ + col;
                    xio[oi] = acc[rt][ct2][jr] + cb + xio[oi];
                }
            }
    }
}

extern "C" void kernel_launch(void* const* d_in, const int* in_sizes, int n_in,
                              void* d_out, int out_size, void* d_ws, size_t ws_size,
                              hipStream_t stream)
{
    const float* x    = (const float*)d_in[0];
    const float* n1g  = (const float*)d_in[1];
    const float* n1b  = (const float*)d_in[2];
    const float* qkvw = (const float*)d_in[3];
    const float* qkvb = (const float*)d_in[4];
    const float* rel  = (const float*)d_in[5];
    const float* pw   = (const float*)d_in[6];
    const float* pb   = (const float*)d_in[7];
    const float* n2g  = (const float*)d_in[8];
    const float* n2b  = (const float*)d_in[9];
    const float* f1w  = (const float*)d_in[10];
    const float* f1b  = (const float*)d_in[11];
    const float* f2w  = (const float*)d_in[12];
    const float* f2b  = (const float*)d_in[13];
    float* out = (float*)d_out;
    u16* ws = (u16*)d_ws;

    prep_w_k<<<768, 256, 0, stream>>>(qkvw, pw, f1w, f2w, ws);
    swin_attn_k<<<4096, 256, 0, stream>>>(x, n1g, n1b, qkvb, rel, pb, ws, out);
    swin_mlp_k<<<6272, 256, 0, stream>>>(out, n2g, n2b, f1b, f2b, ws);
}

// Round 4
// 288.256 us; speedup vs baseline: 8.8138x; 1.6277x over previous
//
#include <hip/hip_runtime.h>
#include <stdint.h>

typedef unsigned short u16;
typedef unsigned int   u32;
typedef __attribute__((ext_vector_type(8))) short bh8;   // 8 bf16
typedef __attribute__((ext_vector_type(4))) float f32x4; // MFMA C/D

#define SCALE 0.17677669529663687f   // 1/sqrt(32)
#define MFMA  __builtin_amdgcn_mfma_f32_16x16x32_bf16

// ws layout (u16 units)
#define WS_QKV  0         // qkvT  [384][128] bf16 (q rows pre-scaled)
#define WS_PROJ 49152     // projT [128][128] bf16, k-permuted
#define WS_F1   65536     // f1T   [512][128] bf16
#define WS_F2   131072    // f2T   [128][512] bf16, k-permuted
#define WS_M    196608    // f32[4cls][4h][16 rtct][64 lane][4 jr]  (byte 393216)
#define WS_QB   327680    // f32[384] qkv bias (q part pre-scaled)

__device__ __forceinline__ u16 f2bf(float f){
    u32 i; __builtin_memcpy(&i,&f,4); i += 0x7fffu + ((i>>16)&1u); return (u16)(i>>16);
}
__device__ __forceinline__ u32 cvtpk(float lo, float hi){
    u32 r; asm("v_cvt_pk_bf16_f32 %0, %1, %2" : "=v"(r) : "v"(lo), "v"(hi)); return r;
}
__device__ __forceinline__ float rcpf(float v){
    float r; asm("v_rcp_f32 %0, %1" : "=v"(r) : "v"(v)); return r;
}
union BH8U { bh8 v; u32 u[4]; };

// ---------------------------------------------------------------------------
// Prep: weights f32->bf16 (transposed, permuted), bias table, mask+bias M.
// ---------------------------------------------------------------------------
__global__ void prep_k(const float* __restrict__ qkvw, const float* __restrict__ projw,
                       const float* __restrict__ f1w,  const float* __restrict__ f2w,
                       const float* __restrict__ rel,  const float* __restrict__ qkvb,
                       u16* __restrict__ ws)
{
    int idx = blockIdx.x * 256 + threadIdx.x;
    if (idx < 49152) {                       // qkvw [128][384] -> [384][128], scale q
        int c = idx / 384, j = idx % 384;
        float v = qkvw[idx] * (j < 128 ? SCALE : 1.0f);
        ws[WS_QKV + j * 128 + c] = f2bf(v);
    } else if (idx < 65536) {                // projw [128][128] -> [j][pi(k)]
        int i = idx - 49152; int k = i >> 7, j = i & 127;
        int pk = (k & ~31) | ((k & 15) << 1) | ((k >> 4) & 1);
        ws[WS_PROJ + j * 128 + pk] = f2bf(projw[i]);
    } else if (idx < 131072) {               // f1w [128][512] -> [512][128]
        int i = idx - 65536; int c = i >> 9, j = i & 511;
        ws[WS_F1 + j * 128 + c] = f2bf(f1w[i]);
    } else if (idx < 196608) {               // f2w [512][128] -> [j][pi(k)]
        int i = idx - 131072; int k = i >> 7, j = i & 127;
        int pk = (k & ~31) | ((k & 15) << 1) | ((k >> 4) & 1);
        ws[WS_F2 + j * 512 + pk] = f2bf(f2w[i]);
    } else if (idx < 262144) {               // M table, fragment-ordered
        int m = idx - 196608;
        int jr = m & 3, lane = (m >> 2) & 63, tct = (m >> 8) & 15;
        int h = (m >> 12) & 3, cls = (m >> 14) & 3;
        int rt = tct >> 2, ct = tct & 3;
        int row = rt * 16 + (lane >> 4) * 4 + jr, key = ct * 16 + (lane & 15);
        float v;
        if (row < 49 && key < 49) {
            int ri = row / 7, rc = row % 7, ki = key / 7, kc = key % 7;
            v = rel[((ri - ki + 6) * 13 + (rc - kc + 6)) * 4 + h];
            int rH = (cls & 2) ? (ri < 4 ? 1 : 2) : 0, rW = (cls & 1) ? (rc < 4 ? 1 : 2) : 0;
            int kH = (cls & 2) ? (ki < 4 ? 1 : 2) : 0, kW = (cls & 1) ? (kc < 4 ? 1 : 2) : 0;
            if (rH * 3 + rW != kH * 3 + kW) v -= 100.0f;
        } else v = -30000.0f;
        ((float*)(ws + WS_M))[m] = v;
    } else if (idx < 262528) {
        int j = idx - 262144;
        ((float*)(ws + WS_QB))[j] = qkvb[j] * (j < 128 ? SCALE : 1.0f);
    }
}

// ---------------------------------------------------------------------------
// Attention: 1 block = one 7x7 window, 4 waves (wave = head). 50 KB LDS.
// q,k via swapped-operand MFMA stay in registers; P tile XOR-swizzled.
// ---------------------------------------------------------------------------
__global__ __launch_bounds__(256, 3) void swin_attn_k(
    const float* __restrict__ x, const float* __restrict__ n1g, const float* __restrict__ n1b,
    const float* __restrict__ projb, const u16* __restrict__ ws, float* __restrict__ out)
{
    __shared__ u16 arena[16384];   // xn[64][136] -> P[4h][64][64] (swz) -> ao[64][136]
    __shared__ u16 vt[9216];       // per head: vT[32][72]
    const int tid = threadIdx.x, h = tid >> 6, lane = tid & 63;
    const int c15 = lane & 15, g = lane >> 4;
    const int m = blockIdx.x, b = m >> 8, hb = (m >> 4) & 15, wb = m & 15;
    const int cls = ((hb == 15) ? 2 : 0) | ((wb == 15) ? 1 : 0);
    const float* QB = (const float*)(ws + WS_QB);
    const float* Mb = (const float*)(ws + WS_M) + (size_t)((cls * 4 + h) * 16) * 256;

    // ---- LN1 + shift -> xn bf16 (4-lane teams; 16 tokens per wave) ----
    {
        const int t = h * 16 + (lane >> 2), ss = lane & 3;
        const int td = (t * 37) >> 8, tm = t - td * 7;
        int hs = hb * 7 + td + 3;  if (hs >= 112) hs -= 112;
        int wsw = wb * 7 + tm + 3; if (wsw >= 112) wsw -= 112;
        const float* px = x + (size_t)((b * 112 + hs) * 112 + wsw) * 128 + ss * 32;
        float4 xv[8];
        #pragma unroll
        for (int i = 0; i < 8; ++i) xv[i] = *(const float4*)(px + i * 4);
        float s = 0.f, q = 0.f;
        #pragma unroll
        for (int i = 0; i < 8; ++i) {
            s += xv[i].x + xv[i].y + xv[i].z + xv[i].w;
            q += xv[i].x*xv[i].x + xv[i].y*xv[i].y + xv[i].z*xv[i].z + xv[i].w*xv[i].w;
        }
        s += __shfl_xor(s, 1); q += __shfl_xor(q, 1);
        s += __shfl_xor(s, 2); q += __shfl_xor(q, 2);
        float mean = s * (1.f/128.f), var = q * (1.f/128.f) - mean * mean;
        float rstd = rsqrtf(var + 1e-5f);
        const float* pg = n1g + ss * 32; const float* pb = n1b + ss * 32;
        #pragma unroll
        for (int i = 0; i < 4; ++i) {
            float4 a = xv[2*i], c = xv[2*i+1];
            float4 g1 = *(const float4*)(pg + i*8),  g2 = *(const float4*)(pg + i*8 + 4);
            float4 b1 = *(const float4*)(pb + i*8),  b2 = *(const float4*)(pb + i*8 + 4);
            uint4 w;
            w.x = cvtpk((a.x-mean)*rstd*g1.x + b1.x, (a.y-mean)*rstd*g1.y + b1.y);
            w.y = cvtpk((a.z-mean)*rstd*g1.z + b1.z, (a.w-mean)*rstd*g1.w + b1.w);
            w.z = cvtpk((c.x-mean)*rstd*g2.x + b2.x, (c.y-mean)*rstd*g2.y + b2.y);
            w.w = cvtpk((c.z-mean)*rstd*g2.z + b2.z, (c.w-mean)*rstd*g2.w + b2.w);
            *(uint4*)&arena[t * 136 + ss * 32 + i * 8] = w;
        }
    }
    __syncthreads();

    // ---- v = xn @ Wv  -> vT in LDS ----
    {
        bh8 avf[2][4];
        #pragma unroll
        for (int jt = 0; jt < 2; ++jt)
            #pragma unroll
            for (int kc = 0; kc < 4; ++kc)
                avf[jt][kc] = *(const bh8*)&ws[WS_QKV + (256 + h*32 + jt*16 + c15)*128 + kc*32 + g*8];
        const float vb0 = QB[256 + h*32 + c15], vb1 = QB[256 + h*32 + 16 + c15];
        #pragma unroll
        for (int tt = 0; tt < 4; ++tt) {
            bh8 xf[4];
            #pragma unroll
            for (int kc = 0; kc < 4; ++kc)
                xf[kc] = *(const bh8*)&arena[(tt*16 + c15)*136 + kc*32 + g*8];
            f32x4 D0 = {0,0,0,0}, D1 = {0,0,0,0};
            #pragma unroll
            for (int kc = 0; kc < 4; ++kc) { D0 = MFMA(xf[kc], avf[0][kc], D0, 0,0,0); D1 = MFMA(xf[kc], avf[1][kc], D1, 0,0,0); }
            uint2 p0, p1;
            p0.x = cvtpk(D0[0]+vb0, D0[1]+vb0); p0.y = cvtpk(D0[2]+vb0, D0[3]+vb0);
            p1.x = cvtpk(D1[0]+vb1, D1[1]+vb1); p1.y = cvtpk(D1[2]+vb1, D1[3]+vb1);
            *(uint2*)&vt[h*2304 + c15*72        + tt*16 + g*4] = p0;
            *(uint2*)&vt[h*2304 + (16+c15)*72   + tt*16 + g*4] = p1;
        }
    }

    // ---- q,k swapped-operand MFMA: fragments straight into registers ----
    bh8 qf[4], kf[4];
    {
        bh8 aqf[2][4], akf[2][4];
        #pragma unroll
        for (int jt = 0; jt < 2; ++jt)
            #pragma unroll
            for (int kc = 0; kc < 4; ++kc) {
                aqf[jt][kc] = *(const bh8*)&ws[WS_QKV + (      h*32 + jt*16 + c15)*128 + kc*32 + g*8];
                akf[jt][kc] = *(const bh8*)&ws[WS_QKV + (128 + h*32 + jt*16 + c15)*128 + kc*32 + g*8];
            }
        const float4 qb0 = *(const float4*)(QB + h*32 + g*4);
        const float4 qb1 = *(const float4*)(QB + h*32 + 16 + g*4);
        const float4 kb0 = *(const float4*)(QB + 128 + h*32 + g*4);
        const float4 kb1 = *(const float4*)(QB + 128 + h*32 + 16 + g*4);
        #pragma unroll
        for (int tt = 0; tt < 4; ++tt) {
            bh8 xf[4];
            #pragma unroll
            for (int kc = 0; kc < 4; ++kc)
                xf[kc] = *(const bh8*)&arena[(tt*16 + c15)*136 + kc*32 + g*8];
            f32x4 Dq0={0,0,0,0}, Dq1={0,0,0,0}, Dk0={0,0,0,0}, Dk1={0,0,0,0};
            #pragma unroll
            for (int kc = 0; kc < 4; ++kc) {
                Dq0 = MFMA(aqf[0][kc], xf[kc], Dq0, 0,0,0);
                Dq1 = MFMA(aqf[1][kc], xf[kc], Dq1, 0,0,0);
                Dk0 = MFMA(akf[0][kc], xf[kc], Dk0, 0,0,0);
                Dk1 = MFMA(akf[1][kc], xf[kc], Dk1, 0,0,0);
            }
            BH8U qu, ku;
            qu.u[0] = cvtpk(Dq0[0]+qb0.x, Dq0[1]+qb0.y); qu.u[1] = cvtpk(Dq0[2]+qb0.z, Dq0[3]+qb0.w);
            qu.u[2] = cvtpk(Dq1[0]+qb1.x, Dq1[1]+qb1.y); qu.u[3] = cvtpk(Dq1[2]+qb1.z, Dq1[3]+qb1.w);
            ku.u[0] = cvtpk(Dk0[0]+kb0.x, Dk0[1]+kb0.y); ku.u[1] = cvtpk(Dk0[2]+kb0.z, Dk0[3]+kb0.w);
            ku.u[2] = cvtpk(Dk1[0]+kb1.x, Dk1[1]+kb1.y); ku.u[3] = cvtpk(Dk1[2]+kb1.z, Dk1[3]+kb1.w);
            qf[tt] = qu.v; kf[tt] = ku.v;
        }
    }
    __syncthreads();   // xn region now free (P aliases it)

    // ---- QK^T with baked bias/mask as acc-init; softmax (no max pass) ----
    f32x4 p[4][4]; f32x4 inv4[4];
    #pragma unroll
    for (int rt = 0; rt < 4; ++rt) {
        #pragma unroll
        for (int ct = 0; ct < 4; ++ct) {
            f32x4 macc = *(const f32x4*)(Mb + (rt*4 + ct)*256 + lane*4);
            p[rt][ct] = MFMA(qf[rt], kf[ct], macc, 0,0,0);
        }
        #pragma unroll
        for (int ct = 0; ct < 4; ++ct)
            #pragma unroll
            for (int jr = 0; jr < 4; ++jr) p[rt][ct][jr] = __expf(p[rt][ct][jr]);
        f32x4 t = p[rt][0] + p[rt][1] + p[rt][2] + p[rt][3];
        #pragma unroll
        for (int jr = 0; jr < 4; ++jr) {
            float v = t[jr];
            v += __shfl_xor(v, 1); v += __shfl_xor(v, 2);
            v += __shfl_xor(v, 4); v += __shfl_xor(v, 8);
            inv4[rt][jr] = rcpf(v);
        }
    }

    // ---- P (raw exp) -> swizzled LDS tile ----
    char* Pbase = (char*)arena + h * 8192;
    #pragma unroll
    for (int rt = 0; rt < 4; ++rt)
        #pragma unroll
        for (int jr = 0; jr < 4; ++jr) {
            const int row = rt*16 + g*4 + jr, sw = (row & 7) << 4;
            #pragma unroll
            for (int ct = 0; ct < 4; ++ct)
                *(u16*)(Pbase + ((row*128 + (ct*16 + c15)*2) ^ sw)) = f2bf(p[rt][ct][jr]);
        }
    asm volatile("s_waitcnt lgkmcnt(0)" ::: "memory");

    // ---- PV ----
    f32x4 o[4][2];
    #pragma unroll
    for (int rt = 0; rt < 4; ++rt) { o[rt][0] = (f32x4){0,0,0,0}; o[rt][1] = (f32x4){0,0,0,0}; }
    {
        bh8 vf[2][2];
        #pragma unroll
        for (int ct = 0; ct < 2; ++ct)
            #pragma unroll
            for (int kc = 0; kc < 2; ++kc)
                vf[ct][kc] = *(const bh8*)&vt[h*2304 + (ct*16 + c15)*72 + kc*32 + g*8];
        #pragma unroll
        for (int rt = 0; rt < 4; ++rt) {
            const int row = rt*16 + c15, sw = (row & 7) << 4;
            #pragma unroll
            for (int kc = 0; kc < 2; ++kc) {
                bh8 pa = *(const bh8*)(Pbase + ((row*128 + kc*64 + g*16) ^ sw));
                o[rt][0] = MFMA(pa, vf[0][kc], o[rt][0], 0,0,0);
                o[rt][1] = MFMA(pa, vf[1][kc], o[rt][1], 0,0,0);
            }
        }
    }
    __syncthreads();   // all PV done; arena free for ao

    // ---- normalized attn-out -> ao (col-interleaved per 32-block) ----
    #pragma unroll
    for (int rt = 0; rt < 4; ++rt)
        #pragma unroll
        for (int jr = 0; jr < 4; ++jr) {
            const int row = rt*16 + g*4 + jr;
            u32 pk_ = cvtpk(o[rt][0][jr] * inv4[rt][jr], o[rt][1][jr] * inv4[rt][jr]);
            *(u32*)&arena[row*136 + h*32 + 2*c15] = pk_;
        }
    __syncthreads();

    // ---- proj + residual + unshift scatter ----
    {
        bh8 wfp[2][4];
        #pragma unroll
        for (int ct2 = 0; ct2 < 2; ++ct2)
            #pragma unroll
            for (int kc = 0; kc < 4; ++kc)
                wfp[ct2][kc] = *(const bh8*)&ws[WS_PROJ + (h*32 + ct2*16 + c15)*128 + kc*32 + g*8];
        f32x4 pacc[4][2];
        #pragma unroll
        for (int rt = 0; rt < 4; ++rt) { pacc[rt][0] = (f32x4){0,0,0,0}; pacc[rt][1] = (f32x4){0,0,0,0}; }
        #pragma unroll
        for (int rt = 0; rt < 4; ++rt) {
            bh8 af[4];
            #pragma unroll
            for (int kc = 0; kc < 4; ++kc)
                af[kc] = *(const bh8*)&arena[(rt*16 + c15)*136 + kc*32 + g*8];
            #pragma unroll
            for (int kc = 0; kc < 4; ++kc) {
                pacc[rt][0] = MFMA(af[kc], wfp[0][kc], pacc[rt][0], 0,0,0);
                pacc[rt][1] = MFMA(af[kc], wfp[1][kc], pacc[rt][1], 0,0,0);
            }
        }
        const int col0 = h*32 + c15, col1 = col0 + 16;
        const float pb0 = projb[col0], pb1 = projb[col1];
        #pragma unroll
        for (int rt = 0; rt < 4; ++rt)
            #pragma unroll
            for (int jr = 0; jr < 4; ++jr) {
                const int t = rt*16 + g*4 + jr;
                if (t < 49) {
                    const int td = (t * 37) >> 8, tm = t - td * 7;
                    int hs = hb*7 + td + 3;  if (hs >= 112) hs -= 112;
                    int wsw = wb*7 + tm + 3; if (wsw >= 112) wsw -= 112;
                    const size_t base = (size_t)((b*112 + hs)*112 + wsw) * 128;
                    out[base + col0] = pacc[rt][0][jr] + pb0 + x[base + col0];
                    out[base + col1] = pacc[rt][1][jr] + pb1 + x[base + col1];
                }
            }
    }
}

// ---------------------------------------------------------------------------
// MLP: 64 tokens/block, h in 4 chunks of 128 cols. 34 KB LDS -> 4 blocks/CU.
// ---------------------------------------------------------------------------
__global__ __launch_bounds__(256, 4) void swin_mlp_k(
    float* __restrict__ xio, const float* __restrict__ n2g, const float* __restrict__ n2b,
    const float* __restrict__ f1b, const float* __restrict__ f2b, const u16* __restrict__ ws)
{
    __shared__ u16 xnb[64 * 136];
    __shared__ u16 hbuf[64 * 136];
    const int tid = threadIdx.x, w = tid >> 6, lane = tid & 63;
    const int c15 = lane & 15, g = lane >> 4;
    const size_t tok0 = (size_t)blockIdx.x * 64;

    // ---- LN2 (4-lane teams) ----
    {
        const int t = w * 16 + (lane >> 2), ss = lane & 3;
        const float* px = xio + (tok0 + t) * 128 + ss * 32;
        float4 xv[8];
        #pragma unroll
        for (int i = 0; i < 8; ++i) xv[i] = *(const float4*)(px + i * 4);
        float s = 0.f, q = 0.f;
        #pragma unroll
        for (int i = 0; i < 8; ++i) {
            s += xv[i].x + xv[i].y + xv[i].z + xv[i].w;
            q += xv[i].x*xv[i].x + xv[i].y*xv[i].y + xv[i].z*xv[i].z + xv[i].w*xv[i].w;
        }
        s += __shfl_xor(s, 1); q += __shfl_xor(q, 1);
        s += __shfl_xor(s, 2); q += __shfl_xor(q, 2);
        float mean = s * (1.f/128.f), var = q * (1.f/128.f) - mean * mean;
        float rstd = rsqrtf(var + 1e-5f);
        const float* pg = n2g + ss * 32; const float* pb = n2b + ss * 32;
        #pragma unroll
        for (int i = 0; i < 4; ++i) {
            float4 a = xv[2*i], c = xv[2*i+1];
            float4 g1 = *(const float4*)(pg + i*8),  g2 = *(const float4*)(pg + i*8 + 4);
            float4 b1 = *(const float4*)(pb + i*8),  b2 = *(const float4*)(pb + i*8 + 4);
            uint4 wv;
            wv.x = cvtpk((a.x-mean)*rstd*g1.x + b1.x, (a.y-mean)*rstd*g1.y + b1.y);
            wv.y = cvtpk((a.z-mean)*rstd*g1.z + b1.z, (a.w-mean)*rstd*g1.w + b1.w);
            wv.z = cvtpk((c.x-mean)*rstd*g2.x + b2.x, (c.y-mean)*rstd*g2.y + b2.y);
            wv.w = cvtpk((c.z-mean)*rstd*g2.z + b2.z, (c.w-mean)*rstd*g2.w + b2.w);
            *(uint4*)&xnb[t * 136 + ss * 32 + i * 8] = wv;
        }
    }
    __syncthreads();

    f32x4 acc[4][2];
    #pragma unroll
    for (int rt = 0; rt < 4; ++rt) { acc[rt][0] = (f32x4){0,0,0,0}; acc[rt][1] = (f32x4){0,0,0,0}; }

    for (int chunk = 0; chunk < 4; ++chunk) {
        // ---- fc1 chunk + GELU -> hbuf ----
        bh8 wf[2][4];
        #pragma unroll
        for (int jt = 0; jt < 2; ++jt)
            #pragma unroll
            for (int kc = 0; kc < 4; ++kc)
                wf[jt][kc] = *(const bh8*)&ws[WS_F1 + (chunk*128 + w*32 + jt*16 + c15)*128 + kc*32 + g*8];
        const float b1s0 = f1b[chunk*128 + w*32 + c15];
        const float b1s1 = f1b[chunk*128 + w*32 + 16 + c15];
        if (chunk) __syncthreads();          // prev fc2 reads of hbuf done
        #pragma unroll
        for (int rt = 0; rt < 4; ++rt) {
            bh8 af[4];
            #pragma unroll
            for (int kc = 0; kc < 4; ++kc)
                af[kc] = *(const bh8*)&xnb[(rt*16 + c15)*136 + kc*32 + g*8];
            f32x4 D0 = {0,0,0,0}, D1 = {0,0,0,0};
            #pragma unroll
            for (int kc = 0; kc < 4; ++kc) { D0 = MFMA(af[kc], wf[0][kc], D0, 0,0,0); D1 = MFMA(af[kc], wf[1][kc], D1, 0,0,0); }
            #pragma unroll
            for (int jr = 0; jr < 4; ++jr) {
                float h0 = D0[jr] + b1s0, h1 = D1[jr] + b1s1;
                h0 = 0.5f * h0 * (1.0f + erff(h0 * 0.70710678118654752f));
                h1 = 0.5f * h1 * (1.0f + erff(h1 * 0.70710678118654752f));
                *(u32*)&hbuf[(rt*16 + g*4 + jr)*136 + w*32 + 2*c15] = cvtpk(h0, h1);
            }
        }
        __syncthreads();
        // ---- fc2 partial ----
        bh8 wf2[2][4];
        #pragma unroll
        for (int ct2 = 0; ct2 < 2; ++ct2)
            #pragma unroll
            for (int kc = 0; kc < 4; ++kc)
                wf2[ct2][kc] = *(const bh8*)&ws[WS_F2 + (w*32 + ct2*16 + c15)*512 + chunk*128 + kc*32 + g*8];
        #pragma unroll
        for (int rt = 0; rt < 4; ++rt) {
            bh8 ha[4];
            #pragma unroll
            for (int kc = 0; kc < 4; ++kc)
                ha[kc] = *(const bh8*)&hbuf[(rt*16 + c15)*136 + kc*32 + g*8];
            #pragma unroll
            for (int kc = 0; kc < 4; ++kc) {
                acc[rt][0] = MFMA(ha[kc], wf2[0][kc], acc[rt][0], 0,0,0);
                acc[rt][1] = MFMA(ha[kc], wf2[1][kc], acc[rt][1], 0,0,0);
            }
        }
    }

    // ---- residual (in place) ----
    const int col0 = w*32 + c15, col1 = col0 + 16;
    const float cb0 = f2b[col0], cb1 = f2b[col1];
    #pragma unroll
    for (int rt = 0; rt < 4; ++rt)
        #pragma unroll
        for (int jr = 0; jr < 4; ++jr) {
            const size_t r = (tok0 + rt*16 + g*4 + jr) * 128;
            xio[r + col0] += acc[rt][0][jr] + cb0;
            xio[r + col1] += acc[rt][1][jr] + cb1;
        }
}

extern "C" void kernel_launch(void* const* d_in, const int* in_sizes, int n_in,
                              void* d_out, int out_size, void* d_ws, size_t ws_size,
                              hipStream_t stream)
{
    const float* x    = (const float*)d_in[0];
    const float* n1g  = (const float*)d_in[1];
    const float* n1b  = (const float*)d_in[2];
    const float* qkvw = (const float*)d_in[3];
    const float* qkvb = (const float*)d_in[4];
    const float* rel  = (const float*)d_in[5];
    const float* pw   = (const float*)d_in[6];
    const float* pb   = (const float*)d_in[7];
    const float* n2g  = (const float*)d_in[8];
    const float* n2b  = (const float*)d_in[9];
    const float* f1w  = (const float*)d_in[10];
    const float* f1b  = (const float*)d_in[11];
    const float* f2w  = (const float*)d_in[12];
    const float* f2b  = (const float*)d_in[13];
    float* out = (float*)d_out;
    u16* ws = (u16*)d_ws;

    prep_k<<<1026, 256, 0, stream>>>(qkvw, pw, f1w, f2w, rel, qkvb, ws);
    swin_attn_k<<<4096, 256, 0, stream>>>(x, n1g, n1b, pb, ws, out);
    swin_mlp_k<<<3136, 256, 0, stream>>>(out, n2g, n2b, f1b, f2b, ws);
}